// Round 1
// baseline (459.955 us; speedup 1.0000x reference)
//
#include <hip/hip_runtime.h>
#include <stdint.h>

typedef __attribute__((ext_vector_type(8))) short short8;
typedef __attribute__((ext_vector_type(4))) float floatx4;

__device__ inline unsigned short f2bf(float f) {
  union { float f; unsigned int u; } v; v.f = f;
  unsigned int u = v.u;
  unsigned int r = (u + 0x7FFFu + ((u >> 16) & 1u)) >> 16;  // RTNE
  return (unsigned short)r;
}

// ---------------- CSR build ----------------
__global__ __launch_bounds__(256) void k_init(int* deg, int* outdeg, int N) {
  int i = blockIdx.x * 256 + threadIdx.x;
  if (i < N) { deg[i] = 0; outdeg[i] = 0; }
}

__global__ __launch_bounds__(256) void k_count(const int* __restrict__ esrc,
                                               const int* __restrict__ edst,
                                               int* deg, int* outdeg, int E) {
  int e = blockIdx.x * 256 + threadIdx.x;
  if (e < E) {
    atomicAdd(&deg[edst[e]], 1);
    atomicAdd(&outdeg[esrc[e]], 1);
  }
}

__global__ __launch_bounds__(1024) void k_scan_local(const int* __restrict__ deg,
                                                     int* __restrict__ off,
                                                     int* __restrict__ bsum, int N) {
  __shared__ int sb[1024];
  int tid = threadIdx.x;
  int i = blockIdx.x * 1024 + tid;
  int v = (i < N) ? deg[i] : 0;
  sb[tid] = v;
  __syncthreads();
  for (int d = 1; d < 1024; d <<= 1) {
    int t = (tid >= d) ? sb[tid - d] : 0;
    __syncthreads();
    sb[tid] += t;
    __syncthreads();
  }
  if (i < N) off[i] = sb[tid] - v;   // block-local exclusive
  if (tid == 1023) bsum[blockIdx.x] = sb[1023];
}

__global__ __launch_bounds__(1024) void k_scan_bsums(int* bsum, int nb) {
  __shared__ int sb[1024];
  int tid = threadIdx.x;
  int v = (tid < nb) ? bsum[tid] : 0;
  sb[tid] = v;
  __syncthreads();
  for (int d = 1; d < 1024; d <<= 1) {
    int t = (tid >= d) ? sb[tid - d] : 0;
    __syncthreads();
    sb[tid] += t;
    __syncthreads();
  }
  if (tid < nb) bsum[tid] = sb[tid] - v;  // exclusive
}

__global__ __launch_bounds__(256) void k_scan_fix(int* off, int* cur,
                                                  const int* __restrict__ bsum,
                                                  const int* __restrict__ outdeg,
                                                  float* invc, int N, int E) {
  int i = blockIdx.x * 256 + threadIdx.x;
  if (i < N) {
    int o = off[i] + bsum[i >> 10];
    off[i] = o;
    cur[i] = o;
    invc[i] = 1.0f / (1.0f + (float)outdeg[i]);  // 1/cnt, cnt = outdeg + self loop
  }
  if (i == 0) off[N] = E;
}

__global__ __launch_bounds__(256) void k_fill(const int* __restrict__ esrc,
                                              const int* __restrict__ edst,
                                              int* cur, int* __restrict__ srcs, int E) {
  int e = blockIdx.x * 256 + threadIdx.x;
  if (e < E) {
    int p = atomicAdd(&cur[edst[e]], 1);
    srcs[p] = esrc[e];
  }
}

// ---------------- bf16 MFMA GEMM: out[N,HOUT] = act(in[N,128] @ W[HOUT,128]^T + b) ----------------
// Block: 256 threads = 4 waves, 64 nodes/block, wave w handles nodes w*16..w*16+15 x all HOUT.
// LDS rows padded to 136 bf16 (272 B) so a/b-frag b128 reads spread evenly over all 8 bank groups.
template <int HOUT, bool RELU_OUT, bool RELU_IN, bool SCALE>
__global__ __launch_bounds__(256) void k_gemm(const float* __restrict__ in,
                                              const float* __restrict__ W,
                                              const float* __restrict__ bias,
                                              const float* __restrict__ scale,
                                              float* out, int N) {
  __shared__ unsigned short sx[64 * 136];
  __shared__ unsigned short sw[HOUT * 136];
  const int tid = threadIdx.x;
  const int nb = blockIdx.x * 64;

  // stage weights (fp32 -> bf16), coalesced float4 reads
  for (int i = tid; i < HOUT * 32; i += 256) {
    int h = i >> 5, k4 = i & 31;
    float4 wv = ((const float4*)W)[i];
    uint2 p;
    p.x = (unsigned int)f2bf(wv.x) | ((unsigned int)f2bf(wv.y) << 16);
    p.y = (unsigned int)f2bf(wv.z) | ((unsigned int)f2bf(wv.w) << 16);
    *(uint2*)&sw[h * 136 + k4 * 4] = p;
  }
  // stage x tile (fp32 -> bf16), optional fused relu on read
  for (int i = tid; i < 64 * 32; i += 256) {
    int n = i >> 5, k4 = i & 31;
    int gn = nb + n;
    float4 xv;
    if (gn < N) xv = ((const float4*)in)[(size_t)gn * 32 + k4];
    else { xv.x = 0.f; xv.y = 0.f; xv.z = 0.f; xv.w = 0.f; }
    if (RELU_IN) {
      xv.x = fmaxf(xv.x, 0.f); xv.y = fmaxf(xv.y, 0.f);
      xv.z = fmaxf(xv.z, 0.f); xv.w = fmaxf(xv.w, 0.f);
    }
    uint2 p;
    p.x = (unsigned int)f2bf(xv.x) | ((unsigned int)f2bf(xv.y) << 16);
    p.y = (unsigned int)f2bf(xv.z) | ((unsigned int)f2bf(xv.w) << 16);
    *(uint2*)&sx[n * 136 + k4 * 4] = p;
  }
  __syncthreads();

  const int wave = tid >> 6, lane = tid & 63;
  const int quad = lane >> 4, lq = lane & 15;
  constexpr int NT = HOUT / 16;
  floatx4 acc[NT];
#pragma unroll
  for (int t = 0; t < NT; ++t) acc[t] = (floatx4){0.f, 0.f, 0.f, 0.f};

  const int arow = (wave * 16 + lq) * 136;
#pragma unroll
  for (int kt = 0; kt < 4; ++kt) {
    short8 a = *(const short8*)&sx[arow + kt * 32 + quad * 8];
#pragma unroll
    for (int t = 0; t < NT; ++t) {
      short8 b = *(const short8*)&sw[(t * 16 + lq) * 136 + kt * 32 + quad * 8];
      acc[t] = __builtin_amdgcn_mfma_f32_16x16x32_bf16(a, b, acc[t], 0, 0, 0);
    }
  }

  // epilogue: D row = quad*4 + r (node), col = lq (h)  [m89-verified layout]
#pragma unroll
  for (int t = 0; t < NT; ++t) {
    int h = t * 16 + lq;
    float bv = bias[h];
#pragma unroll
    for (int r = 0; r < 4; ++r) {
      int n = nb + wave * 16 + quad * 4 + r;
      if (n < N) {
        float v = acc[t][r] + bv;
        if (SCALE) v *= scale[n];
        if (RELU_OUT) v = fmaxf(v, 0.f);
        out[(size_t)n * HOUT + h] = v;
      }
    }
  }
}

// ---------------- CSR gather-sum: out[i] = r(in[i]) + sum_{src->i} r(in[src]) ----------------
template <bool RELU_IN>
__global__ __launch_bounds__(128) void k_aggregate(const float* __restrict__ in,
                                                   float* __restrict__ out,
                                                   const int* __restrict__ off,
                                                   const int* __restrict__ srcs, int N) {
  int i = blockIdx.x;
  int f = threadIdx.x;  // 128 threads = one feature each
  int s = off[i], e = off[i + 1];
  float v = in[(size_t)i * 128 + f];
  if (RELU_IN) v = fmaxf(v, 0.f);
  float acc = v;  // self term (FL self-loop / GIN "x + agg")
  __shared__ int sb[128];
  for (int base = s; base < e; base += 128) {
    int cnt = min(128, e - base);
    __syncthreads();
    if (f < cnt) sb[f] = srcs[base + f];
    __syncthreads();
    for (int j = 0; j < cnt; ++j) {
      float u = in[(size_t)sb[j] * 128 + f];
      if (RELU_IN) u = fmaxf(u, 0.f);
      acc += u;
    }
  }
  out[(size_t)i * 128 + f] = acc;
}

// ---------------- log_softmax over 64 logits, one wave per row, in-place ----------------
__global__ __launch_bounds__(256) void k_logsoftmax(float* out, int N) {
  int row = blockIdx.x * 4 + (threadIdx.x >> 6);
  int lane = threadIdx.x & 63;
  if (row >= N) return;
  float v = out[(size_t)row * 64 + lane];
  float m = v;
  for (int d = 32; d > 0; d >>= 1) m = fmaxf(m, __shfl_xor(m, d));
  float ex = expf(v - m);
  float s = ex;
  for (int d = 32; d > 0; d >>= 1) s += __shfl_xor(s, d);
  out[(size_t)row * 64 + lane] = (v - m) - logf(s);
}

extern "C" void kernel_launch(void* const* d_in, const int* in_sizes, int n_in,
                              void* d_out, int out_size, void* d_ws, size_t ws_size,
                              hipStream_t stream) {
  const float* x     = (const float*)d_in[0];
  const int*   edges = (const int*)  d_in[1];
  const float* fl_W  = (const float*)d_in[2];
  const float* fl_b  = (const float*)d_in[3];
  // d_in[4] fl_att: provably unused — softmax over constant-per-group alpha == 1/count
  const float* g1_W1 = (const float*)d_in[5];
  const float* g1_b1 = (const float*)d_in[6];
  const float* g1_W2 = (const float*)d_in[7];
  const float* g1_b2 = (const float*)d_in[8];
  const float* g2_W1 = (const float*)d_in[9];
  const float* g2_b1 = (const float*)d_in[10];
  const float* g2_W2 = (const float*)d_in[11];
  const float* g2_b2 = (const float*)d_in[12];
  const float* out_W = (const float*)d_in[13];
  const float* out_b = (const float*)d_in[14];

  const int N = in_sizes[0] / 128;
  const int E = in_sizes[1] / 2;
  const int* esrc = edges;       // edge_index[0] (row / message source)
  const int* edst = edges + E;   // edge_index[1] (col / aggregation target)

  char* w = (char*)d_ws;
  float* A = (float*)w;          w += (size_t)N * 128 * 4;
  float* B = (float*)w;          w += (size_t)N * 128 * 4;
  int* deg    = (int*)w;         w += (size_t)N * 4;
  int* outdeg = (int*)w;         w += (size_t)N * 4;
  int* off    = (int*)w;         w += (size_t)(N + 1) * 4;
  int* cur    = (int*)w;         w += (size_t)N * 4;
  float* invc = (float*)w;       w += (size_t)N * 4;
  int* bsum   = (int*)w;         w += 1024 * 4;
  int* srcs   = (int*)w;         w += (size_t)E * 4;

  const int GB = (N + 63) / 64;
  const int nchunk = (N + 1023) / 1024;

  // CSR by destination + degree counts
  k_init<<<(N + 255) / 256, 256, 0, stream>>>(deg, outdeg, N);
  k_count<<<(E + 255) / 256, 256, 0, stream>>>(esrc, edst, deg, outdeg, E);
  k_scan_local<<<nchunk, 1024, 0, stream>>>(deg, off, bsum, N);
  k_scan_bsums<<<1, 1024, 0, stream>>>(bsum, nchunk);
  k_scan_fix<<<(N + 255) / 256, 256, 0, stream>>>(off, cur, bsum, outdeg, invc, N, E);
  k_fill<<<(E + 255) / 256, 256, 0, stream>>>(esrc, edst, cur, srcs, E);

  // FastLocalConv: A = (x @ fl_W^T + b) * (1/cnt) ; B = h1 = A[i] + sum A[src]
  k_gemm<128, false, false, true><<<GB, 256, 0, stream>>>(x, fl_W, fl_b, invc, A, N);
  k_aggregate<false><<<N, 128, 0, stream>>>(A, B, off, srcs, N);

  // GIN1: z1 = relu(h1)[i] + sum relu(h1)[src]; t = relu(z1@W1^T+b1); h2 = t@W2^T+b2
  k_aggregate<true><<<N, 128, 0, stream>>>(B, A, off, srcs, N);
  k_gemm<128, true, false, false><<<GB, 256, 0, stream>>>(A, g1_W1, g1_b1, nullptr, A, N);
  k_gemm<128, false, false, false><<<GB, 256, 0, stream>>>(A, g1_W2, g1_b2, nullptr, A, N);

  // GIN2
  k_aggregate<true><<<N, 128, 0, stream>>>(A, B, off, srcs, N);
  k_gemm<128, true, false, false><<<GB, 256, 0, stream>>>(B, g2_W1, g2_b1, nullptr, B, N);
  k_gemm<128, false, false, false><<<GB, 256, 0, stream>>>(B, g2_W2, g2_b2, nullptr, B, N);

  // head: logits = relu(h3) @ out_W^T + out_b ; then in-place log_softmax
  k_gemm<64, false, true, false><<<GB, 256, 0, stream>>>(B, out_W, out_b, nullptr, (float*)d_out, N);
  k_logsoftmax<<<(N + 3) / 4, 256, 0, stream>>>((float*)d_out, N);
}

// Round 2
// 398.367 us; speedup vs baseline: 1.1546x; 1.1546x over previous
//
#include <hip/hip_runtime.h>
#include <stdint.h>

typedef __attribute__((ext_vector_type(8))) short short8;
typedef __attribute__((ext_vector_type(4))) float floatx4;

__device__ inline unsigned short f2bf(float f) {
  union { float f; unsigned int u; } v; v.f = f;
  unsigned int u = v.u;
  unsigned int r = (u + 0x7FFFu + ((u >> 16) & 1u)) >> 16;  // RTNE
  return (unsigned short)r;
}
__device__ inline float2 up2(unsigned int p) {  // packed bf16x2 -> float2
  float2 r;
  r.x = __uint_as_float(p << 16);
  r.y = __uint_as_float(p & 0xffff0000u);
  return r;
}

// ================= histogram (no global atomics) =================
// 2 node ranges x {dst,src}. Packed u16 bins in LDS; per-block partials to global.
#define HR_BINS 25024            // bins per range (words = 12512)
#define HR_WORDS 12512

template <int LO>
__global__ __launch_bounds__(1024) void k_hist(const int* __restrict__ idx, int E, int per,
                                               unsigned int* __restrict__ partial) {
  __shared__ unsigned int h[HR_WORDS];  // 50 KB
  for (int i = threadIdx.x; i < HR_WORDS; i += 1024) h[i] = 0;
  __syncthreads();
  int s = blockIdx.x * per;
  int e = min(E, s + per);
  for (int j = s + threadIdx.x; j < e; j += 1024) {
    unsigned int d = (unsigned int)(idx[j] - LO);
    if (d < (unsigned int)HR_BINS) atomicAdd(&h[d >> 1], 1u << ((d & 1) * 16));
  }
  __syncthreads();
  unsigned int* p = partial + (size_t)blockIdx.x * HR_WORDS;
  for (int i = threadIdx.x; i < HR_WORDS; i += 1024) p[i] = h[i];
}

__global__ __launch_bounds__(256) void k_hist_reduce(const unsigned int* __restrict__ pD0,
                                                     const unsigned int* __restrict__ pD1,
                                                     const unsigned int* __restrict__ pS0,
                                                     const unsigned int* __restrict__ pS1,
                                                     int nb, int* __restrict__ deg,
                                                     int* __restrict__ outdeg, int N) {
  int w = blockIdx.x * 256 + threadIdx.x;
  if (w >= 2 * HR_WORDS) return;
  const unsigned int* pd = (w < HR_WORDS) ? (pD0 + w) : (pD1 + (w - HR_WORDS));
  const unsigned int* ps = (w < HR_WORDS) ? (pS0 + w) : (pS1 + (w - HR_WORDS));
  unsigned int lo_d = 0, hi_d = 0, lo_s = 0, hi_s = 0;
  for (int b = 0; b < nb; ++b) {
    unsigned int vd = pd[(size_t)b * HR_WORDS];
    unsigned int vs = ps[(size_t)b * HR_WORDS];
    lo_d += vd & 0xffffu; hi_d += vd >> 16;
    lo_s += vs & 0xffffu; hi_s += vs >> 16;
  }
  int i0 = 2 * w, i1 = 2 * w + 1;   // global bin = 2w (+1) for both ranges
  if (i0 < N) { deg[i0] = (int)lo_d; outdeg[i0] = (int)lo_s; }
  if (i1 < N) { deg[i1] = (int)hi_d; outdeg[i1] = (int)hi_s; }
}

// ================= scan =================
__global__ __launch_bounds__(1024) void k_scan_local(const int* __restrict__ deg,
                                                     int* __restrict__ off,
                                                     int* __restrict__ bsum, int N) {
  __shared__ int sb[1024];
  int tid = threadIdx.x;
  int i = blockIdx.x * 1024 + tid;
  int v = (i < N) ? deg[i] : 0;
  sb[tid] = v;
  __syncthreads();
  for (int d = 1; d < 1024; d <<= 1) {
    int t = (tid >= d) ? sb[tid - d] : 0;
    __syncthreads();
    sb[tid] += t;
    __syncthreads();
  }
  if (i < N) off[i] = sb[tid] - v;
  if (tid == 1023) bsum[blockIdx.x] = sb[1023];
}

__global__ __launch_bounds__(1024) void k_scan_bsums(int* bsum, int nb) {
  __shared__ int sb[1024];
  int tid = threadIdx.x;
  int v = (tid < nb) ? bsum[tid] : 0;
  sb[tid] = v;
  __syncthreads();
  for (int d = 1; d < 1024; d <<= 1) {
    int t = (tid >= d) ? sb[tid - d] : 0;
    __syncthreads();
    sb[tid] += t;
    __syncthreads();
  }
  if (tid < nb) bsum[tid] = sb[tid] - v;
}

__global__ __launch_bounds__(256) void k_scan_fix(int* off, int* cur,
                                                  const int* __restrict__ bsum,
                                                  const int* __restrict__ outdeg,
                                                  float* invc, int N, int E) {
  int i = blockIdx.x * 256 + threadIdx.x;
  if (i < N) {
    int o = off[i] + bsum[i >> 10];
    off[i] = o;
    cur[i] = o;
    invc[i] = 1.0f / (1.0f + (float)outdeg[i]);
  }
  if (i == 0) off[N] = E;
}

__global__ __launch_bounds__(256) void k_fill(const int* __restrict__ esrc,
                                              const int* __restrict__ edst,
                                              int* cur, int* __restrict__ srcs, int E) {
  int e = blockIdx.x * 256 + threadIdx.x;
  if (e < E) {
    int p = atomicAdd(&cur[edst[e]], 1);
    srcs[p] = esrc[e];
  }
}

// ================= bf16 MFMA GEMM (HOUT=128), bf16 output =================
// 64 nodes/block, 4 waves; LDS rows padded to 136 shorts (272 B) -> conflict-free b128 reads.
template <bool IN_BF16, bool RELU_OUT, bool SCALE>
__global__ __launch_bounds__(256) void k_gemm128(const void* __restrict__ inv,
                                                 const float* __restrict__ W,
                                                 const float* __restrict__ bias,
                                                 const float* __restrict__ scale,
                                                 unsigned short* __restrict__ out, int N) {
  __shared__ unsigned short sx[64 * 136];
  __shared__ unsigned short sw[128 * 136];
  const int tid = threadIdx.x;
  const int nb = blockIdx.x * 64;

  // stage weights fp32 -> bf16
  for (int i = tid; i < 128 * 32; i += 256) {
    int h = i >> 5, k4 = i & 31;
    float4 wv = ((const float4*)W)[i];
    uint2 p;
    p.x = (unsigned int)f2bf(wv.x) | ((unsigned int)f2bf(wv.y) << 16);
    p.y = (unsigned int)f2bf(wv.z) | ((unsigned int)f2bf(wv.w) << 16);
    *(uint2*)&sw[h * 136 + k4 * 4] = p;
  }
  // stage x tile
  if (IN_BF16) {
    const unsigned short* in = (const unsigned short*)inv;
    for (int i = tid; i < 64 * 16; i += 256) {
      int n = i >> 4, c = i & 15;
      int gn = nb + n;
      short8 t;
      if (gn < N) t = *(const short8*)(in + (size_t)gn * 128 + c * 8);
      else t = (short8){0, 0, 0, 0, 0, 0, 0, 0};
      *(short8*)&sx[n * 136 + c * 8] = t;
    }
  } else {
    const float* in = (const float*)inv;
    for (int i = tid; i < 64 * 32; i += 256) {
      int n = i >> 5, k4 = i & 31;
      int gn = nb + n;
      float4 xv;
      if (gn < N) xv = ((const float4*)in)[(size_t)gn * 32 + k4];
      else { xv.x = 0.f; xv.y = 0.f; xv.z = 0.f; xv.w = 0.f; }
      uint2 p;
      p.x = (unsigned int)f2bf(xv.x) | ((unsigned int)f2bf(xv.y) << 16);
      p.y = (unsigned int)f2bf(xv.z) | ((unsigned int)f2bf(xv.w) << 16);
      *(uint2*)&sx[n * 136 + k4 * 4] = p;
    }
  }
  __syncthreads();

  const int wave = tid >> 6, lane = tid & 63;
  const int quad = lane >> 4, lq = lane & 15;
  floatx4 acc[8];
#pragma unroll
  for (int t = 0; t < 8; ++t) acc[t] = (floatx4){0.f, 0.f, 0.f, 0.f};

  const int arow = (wave * 16 + lq) * 136;
#pragma unroll
  for (int kt = 0; kt < 4; ++kt) {
    short8 a = *(const short8*)&sx[arow + kt * 32 + quad * 8];
#pragma unroll
    for (int t = 0; t < 8; ++t) {
      short8 b = *(const short8*)&sw[(t * 16 + lq) * 136 + kt * 32 + quad * 8];
      acc[t] = __builtin_amdgcn_mfma_f32_16x16x32_bf16(a, b, acc[t], 0, 0, 0);
    }
  }

  // epilogue: row = quad*4 + r, col = lq (m89-verified C/D layout)
#pragma unroll
  for (int t = 0; t < 8; ++t) {
    int h = t * 16 + lq;
    float bv = bias[h];
#pragma unroll
    for (int r = 0; r < 4; ++r) {
      int n = nb + wave * 16 + quad * 4 + r;
      if (n < N) {
        float v = acc[t][r] + bv;
        if (SCALE) v *= scale[n];
        if (RELU_OUT) v = fmaxf(v, 0.f);
        out[(size_t)n * 128 + h] = f2bf(v);
      }
    }
  }
}

// ================= head GEMM (HOUT=64) + fused log_softmax, fp32 out =================
__global__ __launch_bounds__(256) void k_gemm_head(const unsigned short* __restrict__ in,
                                                   const float* __restrict__ W,
                                                   const float* __restrict__ bias,
                                                   float* __restrict__ out, int N) {
  __shared__ unsigned short sx[64 * 136];
  __shared__ unsigned short sw[64 * 136];
  const int tid = threadIdx.x;
  const int nb = blockIdx.x * 64;

  for (int i = tid; i < 64 * 32; i += 256) {
    int h = i >> 5, k4 = i & 31;
    float4 wv = ((const float4*)W)[i];
    uint2 p;
    p.x = (unsigned int)f2bf(wv.x) | ((unsigned int)f2bf(wv.y) << 16);
    p.y = (unsigned int)f2bf(wv.z) | ((unsigned int)f2bf(wv.w) << 16);
    *(uint2*)&sw[h * 136 + k4 * 4] = p;
  }
  for (int i = tid; i < 64 * 16; i += 256) {
    int n = i >> 4, c = i & 15;
    int gn = nb + n;
    short8 t;
    if (gn < N) {
      t = *(const short8*)(in + (size_t)gn * 128 + c * 8);
#pragma unroll
      for (int q = 0; q < 8; ++q) {  // relu in bf16 domain
        unsigned short u = (unsigned short)t[q];
        t[q] = (short)((u & 0x8000u) ? 0 : u);
      }
    } else t = (short8){0, 0, 0, 0, 0, 0, 0, 0};
    *(short8*)&sx[n * 136 + c * 8] = t;
  }
  __syncthreads();

  const int wave = tid >> 6, lane = tid & 63;
  const int quad = lane >> 4, lq = lane & 15;
  floatx4 acc[4];
#pragma unroll
  for (int t = 0; t < 4; ++t) acc[t] = (floatx4){0.f, 0.f, 0.f, 0.f};

  const int arow = (wave * 16 + lq) * 136;
#pragma unroll
  for (int kt = 0; kt < 4; ++kt) {
    short8 a = *(const short8*)&sx[arow + kt * 32 + quad * 8];
#pragma unroll
    for (int t = 0; t < 4; ++t) {
      short8 b = *(const short8*)&sw[(t * 16 + lq) * 136 + kt * 32 + quad * 8];
      acc[t] = __builtin_amdgcn_mfma_f32_16x16x32_bf16(a, b, acc[t], 0, 0, 0);
    }
  }

  float v[4][4];
#pragma unroll
  for (int t = 0; t < 4; ++t) {
    float bv = bias[t * 16 + lq];
#pragma unroll
    for (int r = 0; r < 4; ++r) v[t][r] = acc[t][r] + bv;
  }
  // per row r: logits live in regs t=0..3 across the 16 lanes of this quad
#pragma unroll
  for (int r = 0; r < 4; ++r) {
    float m = fmaxf(fmaxf(v[0][r], v[1][r]), fmaxf(v[2][r], v[3][r]));
    m = fmaxf(m, __shfl_xor(m, 1));
    m = fmaxf(m, __shfl_xor(m, 2));
    m = fmaxf(m, __shfl_xor(m, 4));
    m = fmaxf(m, __shfl_xor(m, 8));
    float s = expf(v[0][r] - m) + expf(v[1][r] - m) + expf(v[2][r] - m) + expf(v[3][r] - m);
    s += __shfl_xor(s, 1);
    s += __shfl_xor(s, 2);
    s += __shfl_xor(s, 4);
    s += __shfl_xor(s, 8);
    float l = m + logf(s);
    int n = nb + wave * 16 + quad * 4 + r;
    if (n < N) {
#pragma unroll
      for (int t = 0; t < 4; ++t) out[(size_t)n * 64 + t * 16 + lq] = v[t][r] - l;
    }
  }
}

// ================= CSR gather-sum (bf16): out[i] = r(in[i]) + sum r(in[src]) =================
// one wave per dst node; ushort2 per lane; 4-deep unroll for memory-level parallelism
template <bool RELU_IN>
__global__ __launch_bounds__(256) void k_aggregate(const unsigned int* __restrict__ in32,
                                                   unsigned int* __restrict__ out32,
                                                   const int* __restrict__ off,
                                                   const int* __restrict__ srcs, int N) {
  int i = blockIdx.x * 4 + (threadIdx.x >> 6);
  if (i >= N) return;
  int lane = threadIdx.x & 63;
  int s = off[i], e = off[i + 1];

  float2 a = up2(in32[(size_t)i * 64 + lane]);
  if (RELU_IN) { a.x = fmaxf(a.x, 0.f); a.y = fmaxf(a.y, 0.f); }
  float acc0 = a.x, acc1 = a.y;

  int j = s;
  for (; j + 4 <= e; j += 4) {
    int s0 = srcs[j], s1 = srcs[j + 1], s2 = srcs[j + 2], s3 = srcs[j + 3];
    unsigned int q0 = in32[(size_t)s0 * 64 + lane];
    unsigned int q1 = in32[(size_t)s1 * 64 + lane];
    unsigned int q2 = in32[(size_t)s2 * 64 + lane];
    unsigned int q3 = in32[(size_t)s3 * 64 + lane];
    float2 f0 = up2(q0), f1 = up2(q1), f2 = up2(q2), f3 = up2(q3);
    if (RELU_IN) {
      f0.x = fmaxf(f0.x, 0.f); f0.y = fmaxf(f0.y, 0.f);
      f1.x = fmaxf(f1.x, 0.f); f1.y = fmaxf(f1.y, 0.f);
      f2.x = fmaxf(f2.x, 0.f); f2.y = fmaxf(f2.y, 0.f);
      f3.x = fmaxf(f3.x, 0.f); f3.y = fmaxf(f3.y, 0.f);
    }
    acc0 += (f0.x + f1.x) + (f2.x + f3.x);
    acc1 += (f0.y + f1.y) + (f2.y + f3.y);
  }
  for (; j < e; ++j) {
    float2 f = up2(in32[(size_t)srcs[j] * 64 + lane]);
    if (RELU_IN) { f.x = fmaxf(f.x, 0.f); f.y = fmaxf(f.y, 0.f); }
    acc0 += f.x; acc1 += f.y;
  }
  out32[(size_t)i * 64 + lane] =
      (unsigned int)f2bf(acc0) | ((unsigned int)f2bf(acc1) << 16);
}

extern "C" void kernel_launch(void* const* d_in, const int* in_sizes, int n_in,
                              void* d_out, int out_size, void* d_ws, size_t ws_size,
                              hipStream_t stream) {
  const float* x     = (const float*)d_in[0];
  const int*   edges = (const int*)  d_in[1];
  const float* fl_W  = (const float*)d_in[2];
  const float* fl_b  = (const float*)d_in[3];
  // d_in[4] fl_att unused: softmax over per-source-constant alpha == 1/count (exact)
  const float* g1_W1 = (const float*)d_in[5];
  const float* g1_b1 = (const float*)d_in[6];
  const float* g1_W2 = (const float*)d_in[7];
  const float* g1_b2 = (const float*)d_in[8];
  const float* g2_W1 = (const float*)d_in[9];
  const float* g2_b1 = (const float*)d_in[10];
  const float* g2_W2 = (const float*)d_in[11];
  const float* g2_b2 = (const float*)d_in[12];
  const float* out_W = (const float*)d_in[13];
  const float* out_b = (const float*)d_in[14];

  const int N = in_sizes[0] / 128;
  const int E = in_sizes[1] / 2;
  const int* esrc = edges;
  const int* edst = edges + E;

  char* w = (char*)d_ws;
  unsigned short* A = (unsigned short*)w;  w += (size_t)N * 128 * 2;
  unsigned short* B = (unsigned short*)w;  w += (size_t)N * 128 * 2;
  int* deg    = (int*)w;  w += (size_t)N * 4;
  int* outdeg = (int*)w;  w += (size_t)N * 4;
  int* off    = (int*)w;  w += (size_t)(N + 1) * 4;
  int* cur    = (int*)w;  w += (size_t)N * 4;
  float* invc = (float*)w; w += (size_t)N * 4;
  int* bsum   = (int*)w;  w += 1024 * 4;
  int* srcs   = (int*)w;  w += (size_t)E * 4;
  const int HB = 128;  // hist blocks
  unsigned int* pD0 = (unsigned int*)w; w += (size_t)HB * HR_WORDS * 4;
  unsigned int* pD1 = (unsigned int*)w; w += (size_t)HB * HR_WORDS * 4;
  unsigned int* pS0 = (unsigned int*)w; w += (size_t)HB * HR_WORDS * 4;
  unsigned int* pS1 = (unsigned int*)w; w += (size_t)HB * HR_WORDS * 4;

  const int GB = (N + 63) / 64;
  const int nchunk = (N + 1023) / 1024;
  const int per = (E + HB - 1) / HB;

  // degree histograms (no global atomics) + CSR offsets
  k_hist<0>       <<<HB, 1024, 0, stream>>>(edst, E, per, pD0);
  k_hist<HR_BINS> <<<HB, 1024, 0, stream>>>(edst, E, per, pD1);
  k_hist<0>       <<<HB, 1024, 0, stream>>>(esrc, E, per, pS0);
  k_hist<HR_BINS> <<<HB, 1024, 0, stream>>>(esrc, E, per, pS1);
  k_hist_reduce<<<(2 * HR_WORDS + 255) / 256, 256, 0, stream>>>(pD0, pD1, pS0, pS1, HB, deg, outdeg, N);
  k_scan_local<<<nchunk, 1024, 0, stream>>>(deg, off, bsum, N);
  k_scan_bsums<<<1, 1024, 0, stream>>>(bsum, nchunk);
  k_scan_fix<<<(N + 255) / 256, 256, 0, stream>>>(off, cur, bsum, outdeg, invc, N, E);
  k_fill<<<(E + 255) / 256, 256, 0, stream>>>(esrc, edst, cur, srcs, E);

  // FastLocal: A = (x @ fl_W^T + b) / cnt ;  B = h1 = A[i] + sum A[src]
  k_gemm128<false, false, true><<<GB, 256, 0, stream>>>(x, fl_W, fl_b, invc, A, N);
  k_aggregate<false><<<(N + 3) / 4, 256, 0, stream>>>((const unsigned int*)A, (unsigned int*)B, off, srcs, N);

  // GIN1: z1 = relu(B)self+sum -> A ; t1 = relu(A@W1+b1) -> B ; h2' = B@W2+b2 -> A
  k_aggregate<true><<<(N + 3) / 4, 256, 0, stream>>>((const unsigned int*)B, (unsigned int*)A, off, srcs, N);
  k_gemm128<true, true, false><<<GB, 256, 0, stream>>>(A, g1_W1, g1_b1, nullptr, B, N);
  k_gemm128<true, false, false><<<GB, 256, 0, stream>>>(B, g1_W2, g1_b2, nullptr, A, N);

  // GIN2: z2 = relu(A)self+sum -> B ; t2 = relu(B@W1+b1) -> A ; h3' = A@W2+b2 -> B
  k_aggregate<true><<<(N + 3) / 4, 256, 0, stream>>>((const unsigned int*)A, (unsigned int*)B, off, srcs, N);
  k_gemm128<true, true, false><<<GB, 256, 0, stream>>>(B, g2_W1, g2_b1, nullptr, A, N);
  k_gemm128<true, false, false><<<GB, 256, 0, stream>>>(A, g2_W2, g2_b2, nullptr, B, N);

  // head: log_softmax(relu(B) @ out_W^T + out_b) fused, fp32 out
  k_gemm_head<<<GB, 256, 0, stream>>>(B, out_W, out_b, (float*)d_out, N);
}

// Round 3
// 324.301 us; speedup vs baseline: 1.4183x; 1.2284x over previous
//
#include <hip/hip_runtime.h>
#include <stdint.h>

typedef __attribute__((ext_vector_type(8))) short short8;
typedef __attribute__((ext_vector_type(4))) float floatx4;

#define HR_BINS 25024   // bins per range
#define HR_WORDS 12512  // packed u16 words per range (50 KB LDS)
#define HB 64           // histogram blocks per (array,range)

__device__ inline unsigned short f2bf(float f) {
  union { float f; unsigned int u; } v; v.f = f;
  unsigned int u = v.u;
  unsigned int r = (u + 0x7FFFu + ((u >> 16) & 1u)) >> 16;  // RTNE
  return (unsigned short)r;
}
__device__ inline float2 up2(unsigned int p) {  // packed bf16x2 -> float2
  float2 r;
  r.x = __uint_as_float(p << 16);
  r.y = __uint_as_float(p & 0xffff0000u);
  return r;
}

// ====== hist: grid (HB, 2*NR). y<NR: dst range y ; y>=NR: src range y-NR ======
__global__ __launch_bounds__(1024) void k_hist(const int* __restrict__ esrc,
                                               const int* __restrict__ edst,
                                               int E, int per, int NR,
                                               unsigned int* __restrict__ pAll) {
  __shared__ unsigned int h[HR_WORDS];
  for (int i = threadIdx.x; i < HR_WORDS; i += 1024) h[i] = 0;
  __syncthreads();
  int yy = blockIdx.y;
  const int* idx = (yy < NR) ? edst : esrc;
  int lo = ((yy < NR) ? yy : (yy - NR)) * HR_BINS;
  int s = blockIdx.x * per, e = min(E, s + per);
  for (int j = s + threadIdx.x; j < e; j += 1024) {
    unsigned int d = (unsigned int)(idx[j] - lo);
    if (d < (unsigned int)HR_BINS) atomicAdd(&h[d >> 1], 1u << ((d & 1) * 16));
  }
  __syncthreads();
  unsigned int* p = pAll + ((size_t)yy * HB + blockIdx.x) * HR_WORDS;
  for (int i = threadIdx.x; i < HR_WORDS; i += 1024) p[i] = h[i];
}

// ====== reduce: deg + invc; exclusive-ize dst partials in place (cross-block bases) ======
__global__ __launch_bounds__(256) void k_reduce(unsigned int* __restrict__ pAll,
                                                int NR, int* __restrict__ deg,
                                                float* __restrict__ invc, int N) {
  int w = blockIdx.x * 256 + threadIdx.x;  // global word over NR*HR_WORDS
  if (w >= NR * HR_WORDS) return;
  int r = w / HR_WORDS, wr = w - r * HR_WORDS;
  // dst slabs (slab index r): running exclusive prefix over blocks, rewrite in place
  unsigned int* pd = pAll + ((size_t)r * HB) * HR_WORDS + wr;
  unsigned int lo_run = 0, hi_run = 0;
  for (int b = 0; b < HB; ++b) {
    unsigned int v = pd[(size_t)b * HR_WORDS];
    pd[(size_t)b * HR_WORDS] = (hi_run << 16) | lo_run;
    lo_run += v & 0xffffu; hi_run += v >> 16;
  }
  // src slabs (slab index NR + r): sums only
  const unsigned int* ps = pAll + ((size_t)(NR + r) * HB) * HR_WORDS + wr;
  unsigned int lo_s = 0, hi_s = 0;
  for (int b = 0; b < HB; ++b) {
    unsigned int v = ps[(size_t)b * HR_WORDS];
    lo_s += v & 0xffffu; hi_s += v >> 16;
  }
  int i0 = r * HR_BINS + 2 * wr, i1 = i0 + 1;
  if (i0 < N) { deg[i0] = (int)lo_run; invc[i0] = 1.0f / (1.0f + (float)lo_s); }
  if (i1 < N) { deg[i1] = (int)hi_run; invc[i1] = 1.0f / (1.0f + (float)hi_s); }
}

// ====== scan ======
__global__ __launch_bounds__(1024) void k_scan_local(const int* __restrict__ deg,
                                                     int* __restrict__ off,
                                                     int* __restrict__ bsum, int N) {
  __shared__ int sb[1024];
  int tid = threadIdx.x;
  int i = blockIdx.x * 1024 + tid;
  int v = (i < N) ? deg[i] : 0;
  sb[tid] = v;
  __syncthreads();
  for (int d = 1; d < 1024; d <<= 1) {
    int t = (tid >= d) ? sb[tid - d] : 0;
    __syncthreads();
    sb[tid] += t;
    __syncthreads();
  }
  if (i < N) off[i] = sb[tid] - v;
  if (tid == 1023) bsum[blockIdx.x] = sb[1023];
}

__global__ __launch_bounds__(256) void k_scan_fix(int* off, const int* __restrict__ bsum,
                                                  int N, int E) {
  int i = blockIdx.x * 256 + threadIdx.x;
  if (i >= N) return;
  int nb = i >> 10;  // uniform within a 256-thread block
  int s = 0;
  for (int c = 0; c < nb; ++c) s += bsum[c];
  off[i] += s;
  if (i == 0) off[N] = E;
}

// ====== fill (no global atomics): rank via LDS hist, base via exclusive partial slab ======
__global__ __launch_bounds__(1024) void k_fill2(const int* __restrict__ esrc,
                                                const int* __restrict__ edst,
                                                int E, int per,
                                                const unsigned int* __restrict__ pAll,
                                                const int* __restrict__ off,
                                                int* __restrict__ srcs) {
  __shared__ unsigned int rk[HR_WORDS];
  for (int i = threadIdx.x; i < HR_WORDS; i += 1024) rk[i] = 0;
  __syncthreads();
  int r = blockIdx.y;
  int lo = r * HR_BINS;
  const unsigned int* slab = pAll + ((size_t)r * HB + blockIdx.x) * HR_WORDS;
  int s = blockIdx.x * per, e = min(E, s + per);
  for (int j = s + threadIdx.x; j < e; j += 1024) {
    unsigned int d = (unsigned int)(edst[j] - lo);
    if (d < (unsigned int)HR_BINS) {
      int sh = (d & 1) * 16;
      unsigned int rank = (atomicAdd(&rk[d >> 1], 1u << sh) >> sh) & 0xffffu;
      unsigned int base = (slab[d >> 1] >> sh) & 0xffffu;
      srcs[off[lo + (int)d] + (int)base + (int)rank] = esrc[j];
    }
  }
}

// ====== FastLocal GEMM: out = bf16((x@W^T + b) * invc), fp32 in ======
__global__ __launch_bounds__(256) void k_gemm_fl(const float* __restrict__ in,
                                                 const float* __restrict__ W,
                                                 const float* __restrict__ bias,
                                                 const float* __restrict__ scale,
                                                 unsigned short* __restrict__ out, int N) {
  __shared__ unsigned short sx[64 * 136];
  __shared__ unsigned short sw[128 * 136];
  const int tid = threadIdx.x;
  const int nb = blockIdx.x * 64;

  for (int i = tid; i < 128 * 32; i += 256) {
    int h = i >> 5, k4 = i & 31;
    float4 wv = ((const float4*)W)[i];
    uint2 p;
    p.x = (unsigned int)f2bf(wv.x) | ((unsigned int)f2bf(wv.y) << 16);
    p.y = (unsigned int)f2bf(wv.z) | ((unsigned int)f2bf(wv.w) << 16);
    *(uint2*)&sw[h * 136 + k4 * 4] = p;
  }
  for (int i = tid; i < 64 * 32; i += 256) {
    int n = i >> 5, k4 = i & 31;
    int gn = nb + n;
    float4 xv;
    if (gn < N) xv = ((const float4*)in)[(size_t)gn * 32 + k4];
    else { xv.x = 0.f; xv.y = 0.f; xv.z = 0.f; xv.w = 0.f; }
    uint2 p;
    p.x = (unsigned int)f2bf(xv.x) | ((unsigned int)f2bf(xv.y) << 16);
    p.y = (unsigned int)f2bf(xv.z) | ((unsigned int)f2bf(xv.w) << 16);
    *(uint2*)&sx[n * 136 + k4 * 4] = p;
  }
  __syncthreads();

  const int wave = tid >> 6, lane = tid & 63;
  const int quad = lane >> 4, lq = lane & 15;
  floatx4 acc[8];
#pragma unroll
  for (int t = 0; t < 8; ++t) acc[t] = (floatx4){0.f, 0.f, 0.f, 0.f};
  const int arow = (wave * 16 + lq) * 136;
#pragma unroll
  for (int kt = 0; kt < 4; ++kt) {
    short8 a = *(const short8*)&sx[arow + kt * 32 + quad * 8];
#pragma unroll
    for (int t = 0; t < 8; ++t) {
      short8 b = *(const short8*)&sw[(t * 16 + lq) * 136 + kt * 32 + quad * 8];
      acc[t] = __builtin_amdgcn_mfma_f32_16x16x32_bf16(a, b, acc[t], 0, 0, 0);
    }
  }
#pragma unroll
  for (int t = 0; t < 8; ++t) {
    int h = t * 16 + lq;
    float bv = bias[h];
#pragma unroll
    for (int r = 0; r < 4; ++r) {
      int n = nb + wave * 16 + quad * 4 + r;
      if (n < N) out[(size_t)n * 128 + h] = f2bf((acc[t][r] + bv) * scale[n]);
    }
  }
}

// ====== fused GIN MLP: out = bf16( relu(z@W1^T+b1) @ W2^T + b2 ), bf16 in/out ======
__global__ __launch_bounds__(256) void k_gemm_gin(const unsigned short* __restrict__ in,
                                                  const float* __restrict__ W1,
                                                  const float* __restrict__ b1,
                                                  const float* __restrict__ W2,
                                                  const float* __restrict__ b2,
                                                  unsigned short* __restrict__ out, int N) {
  __shared__ unsigned short sx[64 * 136];   // x tile, then t tile
  __shared__ unsigned short sw[128 * 136];  // W1, then W2
  const int tid = threadIdx.x;
  const int nb = blockIdx.x * 64;

  for (int i = tid; i < 128 * 32; i += 256) {
    int h = i >> 5, k4 = i & 31;
    float4 wv = ((const float4*)W1)[i];
    uint2 p;
    p.x = (unsigned int)f2bf(wv.x) | ((unsigned int)f2bf(wv.y) << 16);
    p.y = (unsigned int)f2bf(wv.z) | ((unsigned int)f2bf(wv.w) << 16);
    *(uint2*)&sw[h * 136 + k4 * 4] = p;
  }
  for (int i = tid; i < 64 * 16; i += 256) {
    int n = i >> 4, c = i & 15;
    int gn = nb + n;
    short8 t;
    if (gn < N) t = *(const short8*)(in + (size_t)gn * 128 + c * 8);
    else t = (short8){0, 0, 0, 0, 0, 0, 0, 0};
    *(short8*)&sx[n * 136 + c * 8] = t;
  }
  __syncthreads();

  const int wave = tid >> 6, lane = tid & 63;
  const int quad = lane >> 4, lq = lane & 15;
  const int arow = (wave * 16 + lq) * 136;

  floatx4 acc[8];
#pragma unroll
  for (int t = 0; t < 8; ++t) acc[t] = (floatx4){0.f, 0.f, 0.f, 0.f};
#pragma unroll
  for (int kt = 0; kt < 4; ++kt) {
    short8 a = *(const short8*)&sx[arow + kt * 32 + quad * 8];
#pragma unroll
    for (int t = 0; t < 8; ++t) {
      short8 b = *(const short8*)&sw[(t * 16 + lq) * 136 + kt * 32 + quad * 8];
      acc[t] = __builtin_amdgcn_mfma_f32_16x16x32_bf16(a, b, acc[t], 0, 0, 0);
    }
  }
  __syncthreads();  // everyone done reading sx/sw

  // t = relu(acc + b1) -> sx (bf16); stage W2 -> sw
#pragma unroll
  for (int t = 0; t < 8; ++t) {
    int h = t * 16 + lq;
    float bv = b1[h];
#pragma unroll
    for (int r = 0; r < 4; ++r) {
      int row = wave * 16 + quad * 4 + r;
      sx[row * 136 + h] = f2bf(fmaxf(acc[t][r] + bv, 0.f));
    }
  }
  for (int i = tid; i < 128 * 32; i += 256) {
    int h = i >> 5, k4 = i & 31;
    float4 wv = ((const float4*)W2)[i];
    uint2 p;
    p.x = (unsigned int)f2bf(wv.x) | ((unsigned int)f2bf(wv.y) << 16);
    p.y = (unsigned int)f2bf(wv.z) | ((unsigned int)f2bf(wv.w) << 16);
    *(uint2*)&sw[h * 136 + k4 * 4] = p;
  }
  __syncthreads();

#pragma unroll
  for (int t = 0; t < 8; ++t) acc[t] = (floatx4){0.f, 0.f, 0.f, 0.f};
#pragma unroll
  for (int kt = 0; kt < 4; ++kt) {
    short8 a = *(const short8*)&sx[arow + kt * 32 + quad * 8];
#pragma unroll
    for (int t = 0; t < 8; ++t) {
      short8 b = *(const short8*)&sw[(t * 16 + lq) * 136 + kt * 32 + quad * 8];
      acc[t] = __builtin_amdgcn_mfma_f32_16x16x32_bf16(a, b, acc[t], 0, 0, 0);
    }
  }
#pragma unroll
  for (int t = 0; t < 8; ++t) {
    int h = t * 16 + lq;
    float bv = b2[h];
#pragma unroll
    for (int r = 0; r < 4; ++r) {
      int n = nb + wave * 16 + quad * 4 + r;
      if (n < N) out[(size_t)n * 128 + h] = f2bf(acc[t][r] + bv);
    }
  }
}

// ====== head GEMM (HOUT=64) + fused log_softmax, fp32 out ======
__global__ __launch_bounds__(256) void k_gemm_head(const unsigned short* __restrict__ in,
                                                   const float* __restrict__ W,
                                                   const float* __restrict__ bias,
                                                   float* __restrict__ out, int N) {
  __shared__ unsigned short sx[64 * 136];
  __shared__ unsigned short sw[64 * 136];
  const int tid = threadIdx.x;
  const int nb = blockIdx.x * 64;

  for (int i = tid; i < 64 * 32; i += 256) {
    int h = i >> 5, k4 = i & 31;
    float4 wv = ((const float4*)W)[i];
    uint2 p;
    p.x = (unsigned int)f2bf(wv.x) | ((unsigned int)f2bf(wv.y) << 16);
    p.y = (unsigned int)f2bf(wv.z) | ((unsigned int)f2bf(wv.w) << 16);
    *(uint2*)&sw[h * 136 + k4 * 4] = p;
  }
  for (int i = tid; i < 64 * 16; i += 256) {
    int n = i >> 4, c = i & 15;
    int gn = nb + n;
    short8 t;
    if (gn < N) {
      t = *(const short8*)(in + (size_t)gn * 128 + c * 8);
#pragma unroll
      for (int q = 0; q < 8; ++q) {  // relu in bf16 domain
        unsigned short u = (unsigned short)t[q];
        t[q] = (short)((u & 0x8000u) ? 0 : u);
      }
    } else t = (short8){0, 0, 0, 0, 0, 0, 0, 0};
    *(short8*)&sx[n * 136 + c * 8] = t;
  }
  __syncthreads();

  const int wave = tid >> 6, lane = tid & 63;
  const int quad = lane >> 4, lq = lane & 15;
  floatx4 acc[4];
#pragma unroll
  for (int t = 0; t < 4; ++t) acc[t] = (floatx4){0.f, 0.f, 0.f, 0.f};
  const int arow = (wave * 16 + lq) * 136;
#pragma unroll
  for (int kt = 0; kt < 4; ++kt) {
    short8 a = *(const short8*)&sx[arow + kt * 32 + quad * 8];
#pragma unroll
    for (int t = 0; t < 4; ++t) {
      short8 b = *(const short8*)&sw[(t * 16 + lq) * 136 + kt * 32 + quad * 8];
      acc[t] = __builtin_amdgcn_mfma_f32_16x16x32_bf16(a, b, acc[t], 0, 0, 0);
    }
  }
  float v[4][4];
#pragma unroll
  for (int t = 0; t < 4; ++t) {
    float bv = bias[t * 16 + lq];
#pragma unroll
    for (int r = 0; r < 4; ++r) v[t][r] = acc[t][r] + bv;
  }
#pragma unroll
  for (int r = 0; r < 4; ++r) {
    float m = fmaxf(fmaxf(v[0][r], v[1][r]), fmaxf(v[2][r], v[3][r]));
    m = fmaxf(m, __shfl_xor(m, 1));
    m = fmaxf(m, __shfl_xor(m, 2));
    m = fmaxf(m, __shfl_xor(m, 4));
    m = fmaxf(m, __shfl_xor(m, 8));
    float s = expf(v[0][r] - m) + expf(v[1][r] - m) + expf(v[2][r] - m) + expf(v[3][r] - m);
    s += __shfl_xor(s, 1);
    s += __shfl_xor(s, 2);
    s += __shfl_xor(s, 4);
    s += __shfl_xor(s, 8);
    float l = m + logf(s);
    int n = nb + wave * 16 + quad * 4 + r;
    if (n < N) {
#pragma unroll
      for (int t = 0; t < 4; ++t) out[(size_t)n * 64 + t * 16 + lq] = v[t][r] - l;
    }
  }
}

// ====== CSR gather-sum (bf16): out[i] = r(in[i]) + sum r(in[src]) ======
template <bool RELU_IN>
__global__ __launch_bounds__(256) void k_aggregate(const unsigned int* __restrict__ in32,
                                                   unsigned int* __restrict__ out32,
                                                   const int* __restrict__ off,
                                                   const int* __restrict__ srcs, int N) {
  int i = blockIdx.x * 4 + (threadIdx.x >> 6);
  if (i >= N) return;
  int lane = threadIdx.x & 63;
  int s = off[i], e = off[i + 1];

  float2 a = up2(in32[(size_t)i * 64 + lane]);
  if (RELU_IN) { a.x = fmaxf(a.x, 0.f); a.y = fmaxf(a.y, 0.f); }
  float acc0 = a.x, acc1 = a.y;

  int j = s;
  for (; j + 4 <= e; j += 4) {
    int s0 = srcs[j], s1 = srcs[j + 1], s2 = srcs[j + 2], s3 = srcs[j + 3];
    unsigned int q0 = in32[(size_t)s0 * 64 + lane];
    unsigned int q1 = in32[(size_t)s1 * 64 + lane];
    unsigned int q2 = in32[(size_t)s2 * 64 + lane];
    unsigned int q3 = in32[(size_t)s3 * 64 + lane];
    float2 f0 = up2(q0), f1 = up2(q1), f2 = up2(q2), f3 = up2(q3);
    if (RELU_IN) {
      f0.x = fmaxf(f0.x, 0.f); f0.y = fmaxf(f0.y, 0.f);
      f1.x = fmaxf(f1.x, 0.f); f1.y = fmaxf(f1.y, 0.f);
      f2.x = fmaxf(f2.x, 0.f); f2.y = fmaxf(f2.y, 0.f);
      f3.x = fmaxf(f3.x, 0.f); f3.y = fmaxf(f3.y, 0.f);
    }
    acc0 += (f0.x + f1.x) + (f2.x + f3.x);
    acc1 += (f0.y + f1.y) + (f2.y + f3.y);
  }
  for (; j < e; ++j) {
    float2 f = up2(in32[(size_t)srcs[j] * 64 + lane]);
    if (RELU_IN) { f.x = fmaxf(f.x, 0.f); f.y = fmaxf(f.y, 0.f); }
    acc0 += f.x; acc1 += f.y;
  }
  out32[(size_t)i * 64 + lane] =
      (unsigned int)f2bf(acc0) | ((unsigned int)f2bf(acc1) << 16);
}

extern "C" void kernel_launch(void* const* d_in, const int* in_sizes, int n_in,
                              void* d_out, int out_size, void* d_ws, size_t ws_size,
                              hipStream_t stream) {
  const float* x     = (const float*)d_in[0];
  const int*   edges = (const int*)  d_in[1];
  const float* fl_W  = (const float*)d_in[2];
  const float* fl_b  = (const float*)d_in[3];
  // d_in[4] fl_att unused: softmax over per-source-constant alpha == 1/count (exact)
  const float* g1_W1 = (const float*)d_in[5];
  const float* g1_b1 = (const float*)d_in[6];
  const float* g1_W2 = (const float*)d_in[7];
  const float* g1_b2 = (const float*)d_in[8];
  const float* g2_W1 = (const float*)d_in[9];
  const float* g2_b1 = (const float*)d_in[10];
  const float* g2_W2 = (const float*)d_in[11];
  const float* g2_b2 = (const float*)d_in[12];
  const float* out_W = (const float*)d_in[13];
  const float* out_b = (const float*)d_in[14];

  const int N = in_sizes[0] / 128;
  const int E = in_sizes[1] / 2;
  const int* esrc = edges;
  const int* edst = edges + E;
  const int NR = (N + HR_BINS - 1) / HR_BINS;  // ranges covering all nodes

  char* w = (char*)d_ws;
  unsigned short* A = (unsigned short*)w;  w += (size_t)N * 128 * 2;
  unsigned short* B = (unsigned short*)w;  w += (size_t)N * 128 * 2;
  int* deg    = (int*)w;  w += (size_t)NR * HR_BINS * 4;
  int* off    = (int*)w;  w += (size_t)(N + 1) * 4;
  float* invc = (float*)w; w += (size_t)N * 4;
  int* bsum   = (int*)w;  w += 1024 * 4;
  int* srcs   = (int*)w;  w += (size_t)E * 4;
  unsigned int* pAll = (unsigned int*)w; w += (size_t)2 * NR * HB * HR_WORDS * 4;

  const int GB = (N + 63) / 64;
  const int nchunk = (N + 1023) / 1024;
  const int per = (E + HB - 1) / HB;

  // CSR build (no global atomics anywhere)
  k_hist<<<dim3(HB, 2 * NR), 1024, 0, stream>>>(esrc, edst, E, per, NR, pAll);
  k_reduce<<<(NR * HR_WORDS + 255) / 256, 256, 0, stream>>>(pAll, NR, deg, invc, N);
  k_scan_local<<<nchunk, 1024, 0, stream>>>(deg, off, bsum, N);
  k_scan_fix<<<(N + 255) / 256, 256, 0, stream>>>(off, bsum, N, E);
  k_fill2<<<dim3(HB, NR), 1024, 0, stream>>>(esrc, edst, E, per, pAll, off, srcs);

  // FastLocal: A = (x @ fl_W^T + b) / cnt ;  B = h1 = A[i] + sum A[src]
  k_gemm_fl<<<GB, 256, 0, stream>>>(x, fl_W, fl_b, invc, A, N);
  k_aggregate<false><<<(N + 3) / 4, 256, 0, stream>>>((const unsigned int*)A, (unsigned int*)B, off, srcs, N);

  // GIN1: z1 = relu(B)self+sum -> A ; A -> fused MLP -> B
  k_aggregate<true><<<(N + 3) / 4, 256, 0, stream>>>((const unsigned int*)B, (unsigned int*)A, off, srcs, N);
  k_gemm_gin<<<GB, 256, 0, stream>>>(A, g1_W1, g1_b1, g1_W2, g1_b2, B, N);

  // GIN2: z2 = relu(B)self+sum -> A ; A -> fused MLP -> B
  k_aggregate<true><<<(N + 3) / 4, 256, 0, stream>>>((const unsigned int*)B, (unsigned int*)A, off, srcs, N);
  k_gemm_gin<<<GB, 256, 0, stream>>>(A, g2_W1, g2_b1, g2_W2, g2_b2, B, N);

  // head: log_softmax(relu(B) @ out_W^T + out_b) fused, fp32 out
  k_gemm_head<<<GB, 256, 0, stream>>>(B, out_W, out_b, (float*)d_out, N);
}